// Round 5
// baseline (20.485 us; speedup 1.0000x reference)
//
#include <hip/hip_runtime.h>

// Problem constants (fixed by the reference).
#define BB   32
#define HH   512
#define WW   512
#define HCC  256
#define WCC  256
#define NPIX (HH * WW)          // 262144 = 2^18
#define NELEM (BB * NPIX)       // 8388608 floats per output tensor

typedef float f4 __attribute__((ext_vector_type(4)));

#define NB_HALF 8192            // blocks per role (256 thr, 1 float4 each)

// Role-split: blocks [0, NB_HALF) stream-copy y_initial -> out[0..NELEM).
// Blocks [NB_HALF, 2*NB_HALF) compute the paste -> out[NELEM..2*NELEM).
// Each wave touches exactly ONE output stream (pure-stream HBM traffic).
__global__ __launch_bounds__(256) void TransformedSegmentation_84971632984244_kernel(
    const float* __restrict__ y_initial,
    const float* __restrict__ y_cropped,
    const int*   __restrict__ bboxes,
    float*       __restrict__ out)
{
    if (blockIdx.x < NB_HALF) {
        // ---- pure streaming copy: 1R:1W, coalesced float4 ----
        const int e = (blockIdx.x * 256 + threadIdx.x) << 2;
        const f4 v = *reinterpret_cast<const f4*>(y_initial + e);
        *reinterpret_cast<f4*>(out + e) = v;
        return;
    }

    // ---- paste half: nearly pure write + small (L2/L3-resident) gather ----
    const int e = ((blockIdx.x - NB_HALF) * 256 + threadIdx.x) << 2;
    // A wave covers 256 consecutive elements; batch stride 2^18, row stride
    // 2^9 -> b and r are wave-uniform.
    const int b  = __builtin_amdgcn_readfirstlane(e >> 18);
    const int r  = (e >> 9) & (HH - 1);
    const int c0 = e & (WW - 1);

    const int x1 = bboxes[b * 4 + 0];
    const int y1 = bboxes[b * 4 + 1];
    const int x2 = bboxes[b * 4 + 2];
    const int y2 = bboxes[b * 4 + 3];

    f4 o = {0.f, 0.f, 0.f, 0.f};
    if (r >= y1 && r < y2) {                    // wave-uniform branch
        const unsigned h = (unsigned)(y2 - y1); // in [128, 256]
        const unsigned w = (unsigned)(x2 - x1); // in [128, 256]
        // Exact magic division: for d in [128,256], M = floor(2^32/d)+1.
        // For n <= 65280, umulhi(n, M) == floor(n/d) exactly.
        const unsigned mh = 0xFFFFFFFFu / h + 1u;
        const unsigned mw = 0xFFFFFFFFu / w + 1u;
        const unsigned sr = __umulhi((unsigned)(r - y1) * (unsigned)HCC, mh); // [0,255]
        const float* src = y_cropped + (((long)b * HCC + sr) << 8);
#pragma unroll
        for (int j = 0; j < 4; ++j) {
            const int c = c0 + j;
            float pv = 0.f;
            if (c >= x1 && c < x2) {
                const unsigned sc = __umulhi((unsigned)(c - x1) * (unsigned)WCC, mw); // [0,255]
                pv = src[sc];
            }
            o[j] = pv;
        }
    }
    *reinterpret_cast<f4*>(out + NELEM + e) = o;
}

extern "C" void kernel_launch(void* const* d_in, const int* in_sizes, int n_in,
                              void* d_out, int out_size, void* d_ws, size_t ws_size,
                              hipStream_t stream) {
    // Inputs (setup_inputs order): x [unused], y_initial, y_cropped, bboxes
    const float* y_initial = (const float*)d_in[1];
    const float* y_cropped = (const float*)d_in[2];
    const int*   bboxes    = (const int*)d_in[3];
    float*       out       = (float*)d_out;

    const int grid = 2 * NB_HALF;             // 16384 blocks, 256 thr each
    TransformedSegmentation_84971632984244_kernel<<<grid, 256, 0, stream>>>(
        y_initial, y_cropped, bboxes, out);
}